// Round 8
// baseline (934.968 us; speedup 1.0000x reference)
//
#include <hip/hip_runtime.h>
#include <hip/hip_bf16.h>
#include <math.h>

#define N_ATOMS 12000
#define K_NB 32
#define E_EDGES (N_ATOMS*K_NB)   // 384000
#define R_RES 1500
#define P_PAIRS 4096
#define LN_EPS 1e-5f

typedef __attribute__((ext_vector_type(8))) short short8;
typedef __attribute__((ext_vector_type(4))) float f32x4;
typedef __attribute__((ext_vector_type(4))) unsigned int u32x4;

__device__ __forceinline__ f32x4 splat4(float v){ f32x4 r = {v,v,v,v}; return r; }

__device__ __forceinline__ unsigned short f2bf(float f){
  unsigned u = __builtin_bit_cast(unsigned, f);
  u += 0x7FFF + ((u >> 16) & 1);   // RNE
  return (unsigned short)(u >> 16);
}

// atan2 for y >= 0 (y = |cross| here), abs err ~1e-5 rad. ~15 VALU ops vs
// ~50+ for the libm call. rcp + 1 Newton step, deg-11 odd minimax poly.
__device__ __forceinline__ float fast_atan2(float y, float x){
  float ax = fabsf(x);
  float mn = fminf(ax, y);
  float mx = fmaxf(fmaxf(ax, y), 1e-30f);
  float r  = __builtin_amdgcn_rcpf(mx);
  r = r * (2.0f - mx * r);          // Newton: ~1e-7 rel
  float a = mn * r;                 // in [0,1]
  float s = a * a;
  float p = -0.0117212f;
  p = fmaf(p, s,  0.05265332f);
  p = fmaf(p, s, -0.11643287f);
  p = fmaf(p, s,  0.19354346f);
  p = fmaf(p, s, -0.33262347f);
  p = fmaf(p, s,  0.99997726f);
  p = p * a;
  p = (y > ax) ? (1.57079632679f - p) : p;
  p = (x < 0.f) ? (3.14159265359f - p) : p;
  return p;
}

__device__ __forceinline__ float angle3(float ax,float ay,float az,
                                        float bx,float by,float bz){
  float cx = ay*bz - az*by;
  float cy = az*bx - ax*bz;
  float cz = ax*by - ay*bx;
  float cn = sqrtf(cx*cx + cy*cy + cz*cz);
  float dt = ax*bx + ay*by + az*bz;
  return fast_atan2(cn, dt);
}

// ---------------------------------------------------------------------------
// K0: pack f32 weights [K][512] -> bf16 [K/32][512][32] (contiguous 32KB per
// K-chunk; coalesced LDS staging in the GEMM).
// ---------------------------------------------------------------------------
__global__ __launch_bounds__(256) void wpack_kernel(
    const float* __restrict__ w, unsigned short* __restrict__ wp, int Kdim)
{
  int idx = blockIdx.x*256 + threadIdx.x;
  if (idx >= Kdim*512) return;
  int k = idx >> 9, n = idx & 511;
  wp[(size_t)(k>>5)*512*32 + n*32 + (k&31)] = f2bf(w[idx]);
}

// ---------------------------------------------------------------------------
// K1: per-edge PPF -> MLP(4->4)+LN -> a[4] stored as bf16x4 (8B/edge).
// dst = e>>5 by construction (dst = repeat(arange(N), 32)).
// Kept separate from the MFMA stage: gather-latency bound, hides it with TLP
// (fusing via barriers regressed 391->483 us in R5).
// grid: (E/256, 3 radii, 2 sides), block 256.
// ---------------------------------------------------------------------------
__global__ __launch_bounds__(256) void edge_geom_kernel(
    const float* __restrict__ pos_A, const float* __restrict__ nrm_A,
    const float* __restrict__ pos_B, const float* __restrict__ nrm_B,
    const int* __restrict__ edges_A, const int* __restrict__ edges_B,
    const float* __restrict__ w1, const float* __restrict__ b1,
    const float* __restrict__ g1, const float* __restrict__ be1,
    unsigned short* __restrict__ a_rec)
{
  const int r = blockIdx.y;
  const int side = blockIdx.z;
  const float* __restrict__ pos = side ? pos_B : pos_A;
  const float* __restrict__ nrm = side ? nrm_B : nrm_A;
  const int* __restrict__ edges = (side ? edges_B : edges_A) + r*(2*E_EDGES);

  const int e = blockIdx.x*256 + threadIdx.x;
  const int src = edges[e];
  const int dst = e >> 5;

  float psx = pos[src*3+0], psy = pos[src*3+1], psz = pos[src*3+2];
  float pdx = pos[dst*3+0], pdy = pos[dst*3+1], pdz = pos[dst*3+2];
  float dx = psx-pdx, dy = psy-pdy, dz = psz-pdz;
  float nix = nrm[dst*3+0], niy = nrm[dst*3+1], niz = nrm[dst*3+2];
  float njx = nrm[src*3+0], njy = nrm[src*3+1], njz = nrm[src*3+2];

  float f0 = sqrtf(dx*dx + dy*dy + dz*dz);
  float f1 = angle3(nix,niy,niz, dx,dy,dz);
  float f2 = angle3(njx,njy,njz, dx,dy,dz);
  float f3 = angle3(nix,niy,niz, njx,njy,njz);

  const float* w1r  = w1 + r*16;
  const float* b1r  = b1 + r*4;
  const float* g1r  = g1 + r*4;
  const float* be1r = be1 + r*4;
  float h[4]; float s1 = 0.f;
  #pragma unroll
  for (int j = 0; j < 4; ++j) {
    float t = b1r[j] + f0*w1r[j] + f1*w1r[4+j] + f2*w1r[8+j] + f3*w1r[12+j];
    t = fmaxf(t, 0.f);
    h[j] = t; s1 += t;
  }
  float mu1 = s1*0.25f;
  float v1 = 0.f;
  #pragma unroll
  for (int j = 0; j < 4; ++j) { float d = h[j]-mu1; v1 += d*d; }
  float inv1 = rsqrtf(v1*0.25f + LN_EPS);
  float a0 = g1r[0]*(h[0]-mu1)*inv1 + be1r[0];
  float a1 = g1r[1]*(h[1]-mu1)*inv1 + be1r[1];
  float a2 = g1r[2]*(h[2]-mu1)*inv1 + be1r[2];
  float a3 = g1r[3]*(h[3]-mu1)*inv1 + be1r[3];

  ushort4 rec;
  rec.x = f2bf(a0); rec.y = f2bf(a1); rec.z = f2bf(a2); rec.w = f2bf(a3);
  *(ushort4*)(a_rec + ((size_t)(side*3+r)*E_EDGES + e)*4) = rec;
}

// ---------------------------------------------------------------------------
// K2: layer2 (4->128) via MFMA 16x16x32 bf16 (K padded 4->32), + relu + LN
// (stats via 4-hop shfl over 16-lane col groups) + max over each node's 32
// edges. wave = 8 nodes looped; B-fragments/bias/gamma/beta hoisted once per
// wave. Epilogue vectorized on f32x4 (packed-f32). __launch_bounds__(256,5)
// caps VGPR ~102 (R7's 128 VGPR dropped occupancy to 20% and went
// latency-bound); unroll 2 keeps cross-node ILP without register blowup.
// grid: (N/32, 3, 2), block 256 (4 waves).
// ---------------------------------------------------------------------------
__global__ __launch_bounds__(256, 5) void edge_gemm_kernel(
    const unsigned short* __restrict__ a_rec,
    const float* __restrict__ w2, const float* __restrict__ b2,
    const float* __restrict__ g2, const float* __restrict__ be2,
    unsigned short* __restrict__ feats_A, unsigned short* __restrict__ feats_B)
{
  const int r = blockIdx.y;
  const int side = blockIdx.z;
  unsigned short* __restrict__ feats = side ? feats_B : feats_A;

  const int tid  = threadIdx.x;
  const int wv   = tid >> 6;
  const int lane = tid & 63;
  const int l15  = lane & 15;
  const bool live = (lane < 16);

  const float* __restrict__ w2r = w2 + r*512;    // [4][128]

  // ---- hoisted per-wave constants (amortized over 8 nodes) ----
  short8 bfrag[8];
  float bias[8], gg[8], ee[8];
  #pragma unroll
  for (int ct = 0; ct < 8; ++ct) {
    int n = ct*16 + l15;
    float v0 = w2r[0*128+n], v1 = w2r[1*128+n];
    float v2 = w2r[2*128+n], v3 = w2r[3*128+n];
    short8 bf = {0,0,0,0,0,0,0,0};
    bf[0] = live ? (short)f2bf(v0) : (short)0;
    bf[1] = live ? (short)f2bf(v1) : (short)0;
    bf[2] = live ? (short)f2bf(v2) : (short)0;
    bf[3] = live ? (short)f2bf(v3) : (short)0;
    bfrag[ct] = bf;
    bias[ct] = b2[r*128+n];
    gg[ct]   = g2[r*128+n];
    ee[ct]   = be2[r*128+n];
  }

  const int node0 = blockIdx.x*32 + wv*8;
  const unsigned short* __restrict__ arp0 =
      a_rec + ((size_t)(side*3+r)*E_EDGES + (size_t)node0*32)*4;

  const f32x4 zero4 = splat4(0.f);

  #pragma unroll 2
  for (int nd = 0; nd < 8; ++nd) {
    const unsigned short* arp = arp0 + nd*32*4;
    // issue both rt loads up front (ILP over MFMA waits)
    ushort4 a4_0 = *(const ushort4*)(arp + (l15)*4);
    ushort4 a4_1 = *(const ushort4*)(arp + (16 + l15)*4);

    float nodemax[8];
    #pragma unroll
    for (int ct = 0; ct < 8; ++ct) nodemax[ct] = -3.4e38f;

    #pragma unroll
    for (int rt = 0; rt < 2; ++rt) {
      ushort4 a4 = rt ? a4_1 : a4_0;
      unsigned alo = (unsigned)a4.x | ((unsigned)a4.y << 16);
      unsigned ahi = (unsigned)a4.z | ((unsigned)a4.w << 16);
      alo = live ? alo : 0u;
      ahi = live ? ahi : 0u;
      u32x4 pk = {alo, ahi, 0u, 0u};
      short8 af = __builtin_bit_cast(short8, pk);

      f32x4 acc[8];
      #pragma unroll
      for (int ct = 0; ct < 8; ++ct)
        acc[ct] = __builtin_amdgcn_mfma_f32_16x16x32_bf16(af, bfrag[ct], zero4, 0, 0, 0);

      // relu + bias + per-edge LN stats (packed f32, elementwise over rows i)
      f32x4 p = zero4, q = zero4;
      #pragma unroll
      for (int ct = 0; ct < 8; ++ct) {
        f32x4 t = __builtin_elementwise_max(acc[ct] + splat4(bias[ct]), zero4);
        acc[ct] = t;
        p += t;
        q += t * t;
      }
      // butterfly over the 16-lane col group
      #pragma unroll
      for (int m = 1; m < 16; m <<= 1) {
        #pragma unroll
        for (int i = 0; i < 4; ++i) {
          p[i] += __shfl_xor(p[i], m, 64);
          q[i] += __shfl_xor(q[i], m, 64);
        }
      }
      f32x4 mu4  = p * splat4(1.f/128.f);
      f32x4 var4 = __builtin_elementwise_max(q * splat4(1.f/128.f) - mu4*mu4, zero4);
      f32x4 uu, vv;
      #pragma unroll
      for (int i = 0; i < 4; ++i) {
        float inv = rsqrtf(var4[i] + LN_EPS);
        uu[i] = inv; vv[i] = -mu4[i]*inv;
      }
      // LN apply (2 packed fma per ct) + horizontal row-max
      #pragma unroll
      for (int ct = 0; ct < 8; ++ct) {
        f32x4 v = acc[ct]*uu + vv;
        v = splat4(gg[ct])*v + splat4(ee[ct]);
        float m01 = fmaxf(v[0], v[1]);
        float m23 = fmaxf(v[2], v[3]);
        nodemax[ct] = fmaxf(nodemax[ct], fmaxf(m01, m23));
      }
    }

    // cross-quad reduction once per node (was per rt)
    #pragma unroll
    for (int ct = 0; ct < 8; ++ct) {
      float vm = nodemax[ct];
      vm = fmaxf(vm, __shfl_xor(vm, 16, 64));
      vm = fmaxf(vm, __shfl_xor(vm, 32, 64));
      nodemax[ct] = vm;
    }

    if (live) {
      const int gnode = node0 + nd;
      #pragma unroll
      for (int ct = 0; ct < 8; ++ct)
        feats[(size_t)gnode*384 + r*128 + ct*16 + l15] = f2bf(nodemax[ct]);
    }
  }
}

// ---------------------------------------------------------------------------
// K3: out = LN(relu(x @ w + b)) * g + be via MFMA bf16. N fixed = 512.
// Block = 64 rows (4 waves); wave = 16 rows x all 512 cols (LN wave-local).
// x: bf16 [nrows][K]; wp: bf16 [K/32][512][32]; out f32. Packed-f32 epilogue.
// LDS rows padded to 40 ushort (80B) -> 2-way bank aliasing only.
// grid: (ceil(nrows/64), 2 sides), block 256.
// ---------------------------------------------------------------------------
__global__ __launch_bounds__(256) void gemm_ln_kernel(
    const unsigned short* __restrict__ x_A, const unsigned short* __restrict__ x_B,
    const unsigned short* __restrict__ wp,
    const float* __restrict__ b, const float* __restrict__ g,
    const float* __restrict__ be,
    float* __restrict__ out_A, float* __restrict__ out_B,
    int nrows, int Kdim)
{
  const unsigned short* __restrict__ x = blockIdx.y ? x_B : x_A;
  float* __restrict__ out = blockIdx.y ? out_B : out_A;

  __shared__ __align__(16) unsigned short sA[64*40];    // 5 KB
  __shared__ __align__(16) unsigned short sB[512*40];   // 40 KB
  __shared__ float sb[512], sg[512], sbe[512];          // 6 KB

  const int tid  = threadIdx.x;
  const int wv   = tid >> 6;
  const int lane = tid & 63;
  const int l15  = lane & 15;
  const int quad = lane >> 4;
  const int rbase = blockIdx.x * 64;

  sb[tid]      = b[tid];    sb[tid+256]  = b[tid+256];
  sg[tid]      = g[tid];    sg[tid+256]  = g[tid+256];
  sbe[tid]     = be[tid];   sbe[tid+256] = be[tid+256];

  const f32x4 zero4 = splat4(0.f);
  f32x4 acc[32];
  #pragma unroll
  for (int ct = 0; ct < 32; ++ct) acc[ct] = zero4;

  const int nchunk = Kdim >> 5;
  const int arow = tid >> 2, apart = tid & 3;
  int agr = rbase + arow; if (agr >= nrows) agr = nrows - 1;
  const unsigned short* aptr = x + (size_t)agr*Kdim + apart*8;

  for (int kc = 0; kc < nchunk; ++kc) {
    __syncthreads();
    // stage A chunk: 64 rows x 32 k
    *(float4*)&sA[arow*40 + apart*8] = *(const float4*)(aptr + kc*32);
    // stage B chunk: contiguous 32 KB
    {
      const float4* src = (const float4*)(wp + (size_t)kc*512*32);
      #pragma unroll
      for (int i = 0; i < 8; ++i) {
        int fi = tid + i*256;
        int n = fi >> 2, part = fi & 3;
        *(float4*)&sB[n*40 + part*8] = src[fi];
      }
    }
    __syncthreads();
    short8 af = *(short8*)&sA[(wv*16 + l15)*40 + quad*8];
    #pragma unroll
    for (int ct = 0; ct < 32; ++ct) {
      short8 bf = *(short8*)&sB[(ct*16 + l15)*40 + quad*8];
      acc[ct] = __builtin_amdgcn_mfma_f32_16x16x32_bf16(af, bf, acc[ct], 0, 0, 0);
    }
  }

  // epilogue: relu + bias, per-row LN over 512 cols (packed f32)
  f32x4 p = zero4, q = zero4;
  #pragma unroll
  for (int ct = 0; ct < 32; ++ct) {
    f32x4 t = __builtin_elementwise_max(acc[ct] + splat4(sb[ct*16 + l15]), zero4);
    acc[ct] = t;
    p += t;
    q += t * t;
  }
  #pragma unroll
  for (int m = 1; m < 16; m <<= 1) {
    #pragma unroll
    for (int i = 0; i < 4; ++i) {
      p[i] += __shfl_xor(p[i], m, 64);
      q[i] += __shfl_xor(q[i], m, 64);
    }
  }
  f32x4 mu4  = p * splat4(1.f/512.f);
  f32x4 var4 = __builtin_elementwise_max(q * splat4(1.f/512.f) - mu4*mu4, zero4);
  f32x4 uu, vv;
  #pragma unroll
  for (int i = 0; i < 4; ++i) {
    float inv = rsqrtf(var4[i] + LN_EPS);
    uu[i] = inv; vv[i] = -mu4[i]*inv;
  }
  const int row0 = rbase + wv*16 + quad*4;
  #pragma unroll
  for (int ct = 0; ct < 32; ++ct) {
    int gcol = ct*16 + l15;
    f32x4 v = acc[ct]*uu + vv;
    v = splat4(sg[gcol])*v + splat4(sbe[gcol]);
    #pragma unroll
    for (int i = 0; i < 4; ++i) {
      int grow = row0 + i;
      if (grow < nrows)
        out[(size_t)grow*512 + gcol] = v[i];
    }
  }
}

// ---------------------------------------------------------------------------
// residue max over 8 contiguous atoms; f32 in, bf16 out.
// ---------------------------------------------------------------------------
__global__ __launch_bounds__(256) void resmax_kernel(
    const float* __restrict__ ax_A, const float* __restrict__ ax_B,
    unsigned short* __restrict__ rm_A, unsigned short* __restrict__ rm_B)
{
  const float* __restrict__ ax = blockIdx.y ? ax_B : ax_A;
  unsigned short* __restrict__ rm = blockIdx.y ? rm_B : rm_A;
  int idx = blockIdx.x*256 + threadIdx.x;
  if (idx >= R_RES*128) return;
  int rr = idx >> 7, cq = idx & 127;
  const float4* srcp = (const float4*)(ax + (size_t)rr*8*512) + cq;
  float4 m = srcp[0];
  #pragma unroll
  for (int a = 1; a < 8; ++a) {
    float4 v = srcp[(size_t)a*128];
    m.x = fmaxf(m.x, v.x); m.y = fmaxf(m.y, v.y);
    m.z = fmaxf(m.z, v.z); m.w = fmaxf(m.w, v.w);
  }
  ushort4 o;
  o.x = f2bf(m.x); o.y = f2bf(m.y); o.z = f2bf(m.z); o.w = f2bf(m.w);
  *(ushort4*)(rm + (size_t)rr*512 + cq*4) = o;
}

// ---------------------------------------------------------------------------
// out[p] = sigmoid((resx_A[src[p]] - resx_B[tgt[p]]) . lin_w + b)
// ---------------------------------------------------------------------------
__global__ __launch_bounds__(256) void final_kernel(
    const float* __restrict__ resx_A, const float* __restrict__ resx_B,
    const int* __restrict__ src_idx, const int* __restrict__ tgt_idx,
    const float* __restrict__ lin_w, const float* __restrict__ lin_b,
    float* __restrict__ outp)
{
  int p = blockIdx.x*256 + threadIdx.x;
  if (p >= P_PAIRS) return;
  const float4* xa = (const float4*)(resx_A + (size_t)src_idx[p]*512);
  const float4* xb = (const float4*)(resx_B + (size_t)tgt_idx[p]*512);
  const float4* wv = (const float4*)lin_w;
  float acc = 0.f;
  #pragma unroll 4
  for (int i = 0; i < 128; ++i) {
    float4 a = xa[i], b = xb[i], w = wv[i];
    acc += (a.x-b.x)*w.x + (a.y-b.y)*w.y + (a.z-b.z)*w.z + (a.w-b.w)*w.w;
  }
  acc += lin_b[0];
  outp[p] = 1.f/(1.f + expf(-acc));
}

extern "C" void kernel_launch(void* const* d_in, const int* in_sizes, int n_in,
                              void* d_out, int out_size, void* d_ws, size_t ws_size,
                              hipStream_t stream)
{
  const float* pos_A   = (const float*)d_in[0];
  const float* nrm_A   = (const float*)d_in[1];
  const float* pos_B   = (const float*)d_in[2];
  const float* nrm_B   = (const float*)d_in[3];
  const int*   edges_A = (const int*)d_in[4];
  const int*   edges_B = (const int*)d_in[5];
  const int*   src_idx = (const int*)d_in[8];
  const int*   tgt_idx = (const int*)d_in[9];
  const float* conv_w1  = (const float*)d_in[11];
  const float* conv_b1  = (const float*)d_in[12];
  const float* conv_g1  = (const float*)d_in[13];
  const float* conv_be1 = (const float*)d_in[14];
  const float* conv_w2  = (const float*)d_in[15];
  const float* conv_b2  = (const float*)d_in[16];
  const float* conv_g2  = (const float*)d_in[17];
  const float* conv_be2 = (const float*)d_in[18];
  const float* atom_w   = (const float*)d_in[19];
  const float* atom_b   = (const float*)d_in[20];
  const float* atom_g   = (const float*)d_in[21];
  const float* atom_be  = (const float*)d_in[22];
  const float* res_w    = (const float*)d_in[23];
  const float* res_b    = (const float*)d_in[24];
  const float* res_g    = (const float*)d_in[25];
  const float* res_be   = (const float*)d_in[26];
  const float* lin1_w   = (const float*)d_in[27];
  const float* lin1_b   = (const float*)d_in[28];

  unsigned short* feats_A = (unsigned short*)d_ws;                 // 12000*384 bf16
  unsigned short* feats_B = feats_A + (size_t)N_ATOMS*384;
  float* atomx_A = (float*)(feats_B + (size_t)N_ATOMS*384);        // 12000*512 f32
  float* atomx_B = atomx_A + (size_t)N_ATOMS*512;
  unsigned short* rm_A = (unsigned short*)(atomx_B + (size_t)N_ATOMS*512); // 1500*512 bf16
  unsigned short* rm_B = rm_A + (size_t)R_RES*512;
  float* resx_A  = (float*)(rm_B + (size_t)R_RES*512);             // 1500*512 f32
  float* resx_B  = resx_A + (size_t)R_RES*512;
  unsigned short* a_rec = (unsigned short*)(resx_B + (size_t)R_RES*512); // 6*E*4 bf16
  unsigned short* wpA   = a_rec + (size_t)6*E_EDGES*4;             // 12*512*32 bf16
  unsigned short* wpB   = wpA + (size_t)384*512;                   // 16*512*32 bf16

  wpack_kernel<<<(384*512)/256, 256, 0, stream>>>(atom_w, wpA, 384);
  wpack_kernel<<<(512*512)/256, 256, 0, stream>>>(res_w, wpB, 512);

  dim3 gE(E_EDGES/256, 3, 2);
  edge_geom_kernel<<<gE, 256, 0, stream>>>(pos_A, nrm_A, pos_B, nrm_B,
      edges_A, edges_B, conv_w1, conv_b1, conv_g1, conv_be1, a_rec);

  dim3 gG(N_ATOMS/32, 3, 2);
  edge_gemm_kernel<<<gG, 256, 0, stream>>>(a_rec,
      conv_w2, conv_b2, conv_g2, conv_be2, feats_A, feats_B);

  dim3 gAtom((N_ATOMS + 63)/64, 2);
  gemm_ln_kernel<<<gAtom, 256, 0, stream>>>(feats_A, feats_B, wpA,
      atom_b, atom_g, atom_be, atomx_A, atomx_B, N_ATOMS, 384);

  dim3 gRM((R_RES*128)/256, 2);
  resmax_kernel<<<gRM, 256, 0, stream>>>(atomx_A, atomx_B, rm_A, rm_B);

  dim3 gRes((R_RES + 63)/64, 2);
  gemm_ln_kernel<<<gRes, 256, 0, stream>>>(rm_A, rm_B, wpB,
      res_b, res_g, res_be, resx_A, resx_B, R_RES, 512);

  final_kernel<<<(P_PAIRS+255)/256, 256, 0, stream>>>(resx_A, resx_B,
      src_idx, tgt_idx, lin1_w, lin1_b, (float*)d_out);
}

// Round 9
// 357.331 us; speedup vs baseline: 2.6165x; 2.6165x over previous
//
#include <hip/hip_runtime.h>
#include <hip/hip_bf16.h>
#include <math.h>

#define N_ATOMS 12000
#define K_NB 32
#define E_EDGES (N_ATOMS*K_NB)   // 384000
#define R_RES 1500
#define P_PAIRS 4096
#define LN_EPS 1e-5f

typedef __attribute__((ext_vector_type(8))) short short8;
typedef __attribute__((ext_vector_type(4))) float f32x4;
typedef __attribute__((ext_vector_type(4))) unsigned int u32x4;

__device__ __forceinline__ f32x4 splat4(float v){ f32x4 r = {v,v,v,v}; return r; }

__device__ __forceinline__ unsigned short f2bf(float f){
  unsigned u = __builtin_bit_cast(unsigned, f);
  u += 0x7FFF + ((u >> 16) & 1);   // RNE
  return (unsigned short)(u >> 16);
}

// 16-lane sum-to-all on the VALU pipe via DPP (no DS ops, no ds_bpermute
// latency): quad_perm xor1, xor2, row_half_mirror (xor4), row_mirror (xor8).
template<int CTRL>
__device__ __forceinline__ float dpp_add(float v){
  int x = __builtin_amdgcn_mov_dpp(__builtin_bit_cast(int, v), CTRL, 0xf, 0xf, true);
  return v + __builtin_bit_cast(float, x);
}
__device__ __forceinline__ float dpp16sum(float v){
  v = dpp_add<0xB1>(v);    // quad_perm [1,0,3,2]  : xor 1
  v = dpp_add<0x4E>(v);    // quad_perm [2,3,0,1]  : xor 2
  v = dpp_add<0x141>(v);   // row_half_mirror      : xor 4
  v = dpp_add<0x140>(v);   // row_mirror           : xor 8
  return v;
}

// atan2 for y >= 0 (y = |cross| here), abs err ~1e-5 rad.
__device__ __forceinline__ float fast_atan2(float y, float x){
  float ax = fabsf(x);
  float mn = fminf(ax, y);
  float mx = fmaxf(fmaxf(ax, y), 1e-30f);
  float r  = __builtin_amdgcn_rcpf(mx);
  r = r * (2.0f - mx * r);          // Newton: ~1e-7 rel
  float a = mn * r;                 // in [0,1]
  float s = a * a;
  float p = -0.0117212f;
  p = fmaf(p, s,  0.05265332f);
  p = fmaf(p, s, -0.11643287f);
  p = fmaf(p, s,  0.19354346f);
  p = fmaf(p, s, -0.33262347f);
  p = fmaf(p, s,  0.99997726f);
  p = p * a;
  p = (y > ax) ? (1.57079632679f - p) : p;
  p = (x < 0.f) ? (3.14159265359f - p) : p;
  return p;
}

__device__ __forceinline__ float angle3(float ax,float ay,float az,
                                        float bx,float by,float bz){
  float cx = ay*bz - az*by;
  float cy = az*bx - ax*bz;
  float cz = ax*by - ay*bx;
  float cn = sqrtf(cx*cx + cy*cy + cz*cz);
  float dt = ax*bx + ay*by + az*bz;
  return fast_atan2(cn, dt);
}

// ---------------------------------------------------------------------------
// K0: pack f32 weights [K][512] -> bf16 [K/32][512][32].
// ---------------------------------------------------------------------------
__global__ __launch_bounds__(256) void wpack_kernel(
    const float* __restrict__ w, unsigned short* __restrict__ wp, int Kdim)
{
  int idx = blockIdx.x*256 + threadIdx.x;
  if (idx >= Kdim*512) return;
  int k = idx >> 9, n = idx & 511;
  wp[(size_t)(k>>5)*512*32 + n*32 + (k&31)] = f2bf(w[idx]);
}

// ---------------------------------------------------------------------------
// K1: per-edge PPF -> MLP(4->4)+LN -> a[4] bf16x4 (8B/edge). Separate kernel
// on purpose (gather-latency bound; fusing regressed in R5).
// ---------------------------------------------------------------------------
__global__ __launch_bounds__(256) void edge_geom_kernel(
    const float* __restrict__ pos_A, const float* __restrict__ nrm_A,
    const float* __restrict__ pos_B, const float* __restrict__ nrm_B,
    const int* __restrict__ edges_A, const int* __restrict__ edges_B,
    const float* __restrict__ w1, const float* __restrict__ b1,
    const float* __restrict__ g1, const float* __restrict__ be1,
    unsigned short* __restrict__ a_rec)
{
  const int r = blockIdx.y;
  const int side = blockIdx.z;
  const float* __restrict__ pos = side ? pos_B : pos_A;
  const float* __restrict__ nrm = side ? nrm_B : nrm_A;
  const int* __restrict__ edges = (side ? edges_B : edges_A) + r*(2*E_EDGES);

  const int e = blockIdx.x*256 + threadIdx.x;
  const int src = edges[e];
  const int dst = e >> 5;

  float psx = pos[src*3+0], psy = pos[src*3+1], psz = pos[src*3+2];
  float pdx = pos[dst*3+0], pdy = pos[dst*3+1], pdz = pos[dst*3+2];
  float dx = psx-pdx, dy = psy-pdy, dz = psz-pdz;
  float nix = nrm[dst*3+0], niy = nrm[dst*3+1], niz = nrm[dst*3+2];
  float njx = nrm[src*3+0], njy = nrm[src*3+1], njz = nrm[src*3+2];

  float f0 = sqrtf(dx*dx + dy*dy + dz*dz);
  float f1 = angle3(nix,niy,niz, dx,dy,dz);
  float f2 = angle3(njx,njy,njz, dx,dy,dz);
  float f3 = angle3(nix,niy,niz, njx,njy,njz);

  const float* w1r  = w1 + r*16;
  const float* b1r  = b1 + r*4;
  const float* g1r  = g1 + r*4;
  const float* be1r = be1 + r*4;
  float h[4]; float s1 = 0.f;
  #pragma unroll
  for (int j = 0; j < 4; ++j) {
    float t = b1r[j] + f0*w1r[j] + f1*w1r[4+j] + f2*w1r[8+j] + f3*w1r[12+j];
    t = fmaxf(t, 0.f);
    h[j] = t; s1 += t;
  }
  float mu1 = s1*0.25f;
  float v1 = 0.f;
  #pragma unroll
  for (int j = 0; j < 4; ++j) { float d = h[j]-mu1; v1 += d*d; }
  float inv1 = rsqrtf(v1*0.25f + LN_EPS);
  float a0 = g1r[0]*(h[0]-mu1)*inv1 + be1r[0];
  float a1 = g1r[1]*(h[1]-mu1)*inv1 + be1r[1];
  float a2 = g1r[2]*(h[2]-mu1)*inv1 + be1r[2];
  float a3 = g1r[3]*(h[3]-mu1)*inv1 + be1r[3];

  ushort4 rec;
  rec.x = f2bf(a0); rec.y = f2bf(a1); rec.z = f2bf(a2); rec.w = f2bf(a3);
  *(ushort4*)(a_rec + ((size_t)(side*3+r)*E_EDGES + e)*4) = rec;
}

// ---------------------------------------------------------------------------
// K2: layer2 (4->128) via MFMA 16x16x32 bf16 + relu + per-edge LN + node max.
// R6 structure (scalar stats epilogue, VGPR ~80, NO launch_bounds cap — R8's
// (256,5) cap caused scratch spills: FETCH 9MB->2GB). LN-stats butterfly on
// the VALU pipe via DPP (dpp16sum) instead of 64 ds_bpermute per node.
// grid: (N/32, 3, 2), block 256 (4 waves), wave = 8 nodes looped.
// ---------------------------------------------------------------------------
__global__ __launch_bounds__(256) void edge_gemm_kernel(
    const unsigned short* __restrict__ a_rec,
    const float* __restrict__ w2, const float* __restrict__ b2,
    const float* __restrict__ g2, const float* __restrict__ be2,
    unsigned short* __restrict__ feats_A, unsigned short* __restrict__ feats_B)
{
  const int r = blockIdx.y;
  const int side = blockIdx.z;
  unsigned short* __restrict__ feats = side ? feats_B : feats_A;

  const int tid  = threadIdx.x;
  const int wv   = tid >> 6;
  const int lane = tid & 63;
  const int l15  = lane & 15;
  const bool live = (lane < 16);

  const float* __restrict__ w2r = w2 + r*512;    // [4][128]

  // hoisted per-wave constants (amortized over 8 nodes)
  short8 bfrag[8];
  float bias[8], gg[8], ee[8];
  #pragma unroll
  for (int ct = 0; ct < 8; ++ct) {
    int n = ct*16 + l15;
    float v0 = w2r[0*128+n], v1 = w2r[1*128+n];
    float v2 = w2r[2*128+n], v3 = w2r[3*128+n];
    short8 bf = {0,0,0,0,0,0,0,0};
    bf[0] = live ? (short)f2bf(v0) : (short)0;
    bf[1] = live ? (short)f2bf(v1) : (short)0;
    bf[2] = live ? (short)f2bf(v2) : (short)0;
    bf[3] = live ? (short)f2bf(v3) : (short)0;
    bfrag[ct] = bf;
    bias[ct] = b2[r*128+n];
    gg[ct]   = g2[r*128+n];
    ee[ct]   = be2[r*128+n];
  }

  const int node0 = blockIdx.x*32 + wv*8;
  const unsigned short* __restrict__ arp0 =
      a_rec + ((size_t)(side*3+r)*E_EDGES + (size_t)node0*32)*4;

  const f32x4 zero4 = splat4(0.f);

  for (int nd = 0; nd < 8; ++nd) {
    const unsigned short* arp = arp0 + nd*32*4;
    ushort4 a4_0 = *(const ushort4*)(arp + (l15)*4);
    ushort4 a4_1 = *(const ushort4*)(arp + (16 + l15)*4);

    float nodemax[8];
    #pragma unroll
    for (int ct = 0; ct < 8; ++ct) nodemax[ct] = -3.4e38f;

    #pragma unroll
    for (int rt = 0; rt < 2; ++rt) {
      ushort4 a4 = rt ? a4_1 : a4_0;
      unsigned alo = (unsigned)a4.x | ((unsigned)a4.y << 16);
      unsigned ahi = (unsigned)a4.z | ((unsigned)a4.w << 16);
      alo = live ? alo : 0u;
      ahi = live ? ahi : 0u;
      u32x4 pk = {alo, ahi, 0u, 0u};
      short8 af = __builtin_bit_cast(short8, pk);

      f32x4 acc[8];
      #pragma unroll
      for (int ct = 0; ct < 8; ++ct)
        acc[ct] = __builtin_amdgcn_mfma_f32_16x16x32_bf16(af, bfrag[ct], zero4, 0, 0, 0);

      // relu + bias + per-edge LN stats (scalar loops — R6's 80-VGPR profile)
      float p[4] = {0,0,0,0}, q[4] = {0,0,0,0};
      #pragma unroll
      for (int ct = 0; ct < 8; ++ct) {
        #pragma unroll
        for (int i = 0; i < 4; ++i) {
          float t = fmaxf(acc[ct][i] + bias[ct], 0.f);
          acc[ct][i] = t; p[i] += t; q[i] = fmaf(t, t, q[i]);
        }
      }
      // 16-lane reduction on the VALU pipe (DPP), zero DS ops
      #pragma unroll
      for (int i = 0; i < 4; ++i) {
        p[i] = dpp16sum(p[i]);
        q[i] = dpp16sum(q[i]);
      }
      float uu[4], vv[4];
      #pragma unroll
      for (int i = 0; i < 4; ++i) {
        float mu  = p[i]*(1.f/128.f);
        float var = fmaxf(q[i]*(1.f/128.f) - mu*mu, 0.f);
        float inv = rsqrtf(var + LN_EPS);
        uu[i] = inv; vv[i] = -mu*inv;
      }
      // LN apply + horizontal row-max
      #pragma unroll
      for (int ct = 0; ct < 8; ++ct) {
        float vm = -3.4e38f;
        #pragma unroll
        for (int i = 0; i < 4; ++i) {
          float val = gg[ct]*fmaf(acc[ct][i], uu[i], vv[i]) + ee[ct];
          vm = fmaxf(vm, val);
        }
        nodemax[ct] = fmaxf(nodemax[ct], vm);
      }
    }

    // cross-quad reduction once per node (xor16/32 not expressible as row-DPP)
    #pragma unroll
    for (int ct = 0; ct < 8; ++ct) {
      float vm = nodemax[ct];
      vm = fmaxf(vm, __shfl_xor(vm, 16, 64));
      vm = fmaxf(vm, __shfl_xor(vm, 32, 64));
      nodemax[ct] = vm;
    }

    if (live) {
      const int gnode = node0 + nd;
      #pragma unroll
      for (int ct = 0; ct < 8; ++ct)
        feats[(size_t)gnode*384 + r*128 + ct*16 + l15] = f2bf(nodemax[ct]);
    }
  }
}

// ---------------------------------------------------------------------------
// K3: out = LN(relu(x @ w + b)) * g + be via MFMA bf16. N fixed = 512.
// Block = 64 rows (4 waves); wave = 16 rows x all 512 cols (LN wave-local).
// ---------------------------------------------------------------------------
__global__ __launch_bounds__(256) void gemm_ln_kernel(
    const unsigned short* __restrict__ x_A, const unsigned short* __restrict__ x_B,
    const unsigned short* __restrict__ wp,
    const float* __restrict__ b, const float* __restrict__ g,
    const float* __restrict__ be,
    float* __restrict__ out_A, float* __restrict__ out_B,
    int nrows, int Kdim)
{
  const unsigned short* __restrict__ x = blockIdx.y ? x_B : x_A;
  float* __restrict__ out = blockIdx.y ? out_B : out_A;

  __shared__ __align__(16) unsigned short sA[64*40];    // 5 KB
  __shared__ __align__(16) unsigned short sB[512*40];   // 40 KB
  __shared__ float sb[512], sg[512], sbe[512];          // 6 KB

  const int tid  = threadIdx.x;
  const int wv   = tid >> 6;
  const int lane = tid & 63;
  const int l15  = lane & 15;
  const int quad = lane >> 4;
  const int rbase = blockIdx.x * 64;

  sb[tid]      = b[tid];    sb[tid+256]  = b[tid+256];
  sg[tid]      = g[tid];    sg[tid+256]  = g[tid+256];
  sbe[tid]     = be[tid];   sbe[tid+256] = be[tid+256];

  const f32x4 zero4 = splat4(0.f);
  f32x4 acc[32];
  #pragma unroll
  for (int ct = 0; ct < 32; ++ct) acc[ct] = zero4;

  const int nchunk = Kdim >> 5;
  const int arow = tid >> 2, apart = tid & 3;
  int agr = rbase + arow; if (agr >= nrows) agr = nrows - 1;
  const unsigned short* aptr = x + (size_t)agr*Kdim + apart*8;

  for (int kc = 0; kc < nchunk; ++kc) {
    __syncthreads();
    *(float4*)&sA[arow*40 + apart*8] = *(const float4*)(aptr + kc*32);
    {
      const float4* src = (const float4*)(wp + (size_t)kc*512*32);
      #pragma unroll
      for (int i = 0; i < 8; ++i) {
        int fi = tid + i*256;
        int n = fi >> 2, part = fi & 3;
        *(float4*)&sB[n*40 + part*8] = src[fi];
      }
    }
    __syncthreads();
    short8 af = *(short8*)&sA[(wv*16 + l15)*40 + quad*8];
    #pragma unroll
    for (int ct = 0; ct < 32; ++ct) {
      short8 bf = *(short8*)&sB[(ct*16 + l15)*40 + quad*8];
      acc[ct] = __builtin_amdgcn_mfma_f32_16x16x32_bf16(af, bf, acc[ct], 0, 0, 0);
    }
  }

  // epilogue: relu + bias, per-row LN over 512 cols (packed f32 + DPP hops)
  f32x4 p = zero4, q = zero4;
  #pragma unroll
  for (int ct = 0; ct < 32; ++ct) {
    f32x4 t = __builtin_elementwise_max(acc[ct] + splat4(sb[ct*16 + l15]), zero4);
    acc[ct] = t;
    p += t;
    q += t * t;
  }
  #pragma unroll
  for (int i = 0; i < 4; ++i) {
    p[i] = dpp16sum(p[i]);
    q[i] = dpp16sum(q[i]);
  }
  f32x4 mu4  = p * splat4(1.f/512.f);
  f32x4 var4 = __builtin_elementwise_max(q * splat4(1.f/512.f) - mu4*mu4, zero4);
  f32x4 uu, vv;
  #pragma unroll
  for (int i = 0; i < 4; ++i) {
    float inv = rsqrtf(var4[i] + LN_EPS);
    uu[i] = inv; vv[i] = -mu4[i]*inv;
  }
  const int row0 = rbase + wv*16 + quad*4;
  #pragma unroll
  for (int ct = 0; ct < 32; ++ct) {
    int gcol = ct*16 + l15;
    f32x4 v = acc[ct]*uu + vv;
    v = splat4(sg[gcol])*v + splat4(sbe[gcol]);
    #pragma unroll
    for (int i = 0; i < 4; ++i) {
      int grow = row0 + i;
      if (grow < nrows)
        out[(size_t)grow*512 + gcol] = v[i];
    }
  }
}

// ---------------------------------------------------------------------------
// residue max over 8 contiguous atoms; f32 in, bf16 out.
// ---------------------------------------------------------------------------
__global__ __launch_bounds__(256) void resmax_kernel(
    const float* __restrict__ ax_A, const float* __restrict__ ax_B,
    unsigned short* __restrict__ rm_A, unsigned short* __restrict__ rm_B)
{
  const float* __restrict__ ax = blockIdx.y ? ax_B : ax_A;
  unsigned short* __restrict__ rm = blockIdx.y ? rm_B : rm_A;
  int idx = blockIdx.x*256 + threadIdx.x;
  if (idx >= R_RES*128) return;
  int rr = idx >> 7, cq = idx & 127;
  const float4* srcp = (const float4*)(ax + (size_t)rr*8*512) + cq;
  float4 m = srcp[0];
  #pragma unroll
  for (int a = 1; a < 8; ++a) {
    float4 v = srcp[(size_t)a*128];
    m.x = fmaxf(m.x, v.x); m.y = fmaxf(m.y, v.y);
    m.z = fmaxf(m.z, v.z); m.w = fmaxf(m.w, v.w);
  }
  ushort4 o;
  o.x = f2bf(m.x); o.y = f2bf(m.y); o.z = f2bf(m.z); o.w = f2bf(m.w);
  *(ushort4*)(rm + (size_t)rr*512 + cq*4) = o;
}

// ---------------------------------------------------------------------------
// out[p] = sigmoid((resx_A[src[p]] - resx_B[tgt[p]]) . lin_w + b)
// ---------------------------------------------------------------------------
__global__ __launch_bounds__(256) void final_kernel(
    const float* __restrict__ resx_A, const float* __restrict__ resx_B,
    const int* __restrict__ src_idx, const int* __restrict__ tgt_idx,
    const float* __restrict__ lin_w, const float* __restrict__ lin_b,
    float* __restrict__ outp)
{
  int p = blockIdx.x*256 + threadIdx.x;
  if (p >= P_PAIRS) return;
  const float4* xa = (const float4*)(resx_A + (size_t)src_idx[p]*512);
  const float4* xb = (const float4*)(resx_B + (size_t)tgt_idx[p]*512);
  const float4* wv = (const float4*)lin_w;
  float acc = 0.f;
  #pragma unroll 4
  for (int i = 0; i < 128; ++i) {
    float4 a = xa[i], b = xb[i], w = wv[i];
    acc += (a.x-b.x)*w.x + (a.y-b.y)*w.y + (a.z-b.z)*w.z + (a.w-b.w)*w.w;
  }
  acc += lin_b[0];
  outp[p] = 1.f/(1.f + expf(-acc));
}

extern "C" void kernel_launch(void* const* d_in, const int* in_sizes, int n_in,
                              void* d_out, int out_size, void* d_ws, size_t ws_size,
                              hipStream_t stream)
{
  const float* pos_A   = (const float*)d_in[0];
  const float* nrm_A   = (const float*)d_in[1];
  const float* pos_B   = (const float*)d_in[2];
  const float* nrm_B   = (const float*)d_in[3];
  const int*   edges_A = (const int*)d_in[4];
  const int*   edges_B = (const int*)d_in[5];
  const int*   src_idx = (const int*)d_in[8];
  const int*   tgt_idx = (const int*)d_in[9];
  const float* conv_w1  = (const float*)d_in[11];
  const float* conv_b1  = (const float*)d_in[12];
  const float* conv_g1  = (const float*)d_in[13];
  const float* conv_be1 = (const float*)d_in[14];
  const float* conv_w2  = (const float*)d_in[15];
  const float* conv_b2  = (const float*)d_in[16];
  const float* conv_g2  = (const float*)d_in[17];
  const float* conv_be2 = (const float*)d_in[18];
  const float* atom_w   = (const float*)d_in[19];
  const float* atom_b   = (const float*)d_in[20];
  const float* atom_g   = (const float*)d_in[21];
  const float* atom_be  = (const float*)d_in[22];
  const float* res_w    = (const float*)d_in[23];
  const float* res_b    = (const float*)d_in[24];
  const float* res_g    = (const float*)d_in[25];
  const float* res_be   = (const float*)d_in[26];
  const float* lin1_w   = (const float*)d_in[27];
  const float* lin1_b   = (const float*)d_in[28];

  unsigned short* feats_A = (unsigned short*)d_ws;                 // 12000*384 bf16
  unsigned short* feats_B = feats_A + (size_t)N_ATOMS*384;
  float* atomx_A = (float*)(feats_B + (size_t)N_ATOMS*384);        // 12000*512 f32
  float* atomx_B = atomx_A + (size_t)N_ATOMS*512;
  unsigned short* rm_A = (unsigned short*)(atomx_B + (size_t)N_ATOMS*512); // 1500*512 bf16
  unsigned short* rm_B = rm_A + (size_t)R_RES*512;
  float* resx_A  = (float*)(rm_B + (size_t)R_RES*512);             // 1500*512 f32
  float* resx_B  = resx_A + (size_t)R_RES*512;
  unsigned short* a_rec = (unsigned short*)(resx_B + (size_t)R_RES*512); // 6*E*4 bf16
  unsigned short* wpA   = a_rec + (size_t)6*E_EDGES*4;             // 12*512*32 bf16
  unsigned short* wpB   = wpA + (size_t)384*512;                   // 16*512*32 bf16

  wpack_kernel<<<(384*512)/256, 256, 0, stream>>>(atom_w, wpA, 384);
  wpack_kernel<<<(512*512)/256, 256, 0, stream>>>(res_w, wpB, 512);

  dim3 gE(E_EDGES/256, 3, 2);
  edge_geom_kernel<<<gE, 256, 0, stream>>>(pos_A, nrm_A, pos_B, nrm_B,
      edges_A, edges_B, conv_w1, conv_b1, conv_g1, conv_be1, a_rec);

  dim3 gG(N_ATOMS/32, 3, 2);
  edge_gemm_kernel<<<gG, 256, 0, stream>>>(a_rec,
      conv_w2, conv_b2, conv_g2, conv_be2, feats_A, feats_B);

  dim3 gAtom((N_ATOMS + 63)/64, 2);
  gemm_ln_kernel<<<gAtom, 256, 0, stream>>>(feats_A, feats_B, wpA,
      atom_b, atom_g, atom_be, atomx_A, atomx_B, N_ATOMS, 384);

  dim3 gRM((R_RES*128)/256, 2);
  resmax_kernel<<<gRM, 256, 0, stream>>>(atomx_A, atomx_B, rm_A, rm_B);

  dim3 gRes((R_RES + 63)/64, 2);
  gemm_ln_kernel<<<gRes, 256, 0, stream>>>(rm_A, rm_B, wpB,
      res_b, res_g, res_be, resx_A, resx_B, R_RES, 512);

  final_kernel<<<(P_PAIRS+255)/256, 256, 0, stream>>>(resx_A, resx_B,
      src_idx, tgt_idx, lin1_w, lin1_b, (float*)d_out);
}